// Round 8
// baseline (266.663 us; speedup 1.0000x reference)
//
#include <hip/hip_runtime.h>

constexpr int NNODES = 50000;
constexpr int NEDGES = 800000;
constexpr int CAP = 64;   // bucket capacity; deg ~ Poisson(16), P(deg>=64) ~ 1e-19

typedef __attribute__((ext_vector_type(8))) short short8;    // 8 bf16 (4 VGPRs)
typedef __attribute__((ext_vector_type(8))) unsigned short ushort8;
typedef __attribute__((ext_vector_type(4))) float f32x4;

__device__ __forceinline__ unsigned short f2b(float f) {   // fp32 -> bf16 RTN-even
    unsigned int u = __float_as_uint(f);
    u += 0x7FFFu + ((u >> 16) & 1u);
    return (unsigned short)(u >> 16);
}
__device__ __forceinline__ float b2f(unsigned short u) {   // exact
    return __uint_as_float(((unsigned int)u) << 16);
}

// ---------------------------------------------------------------------------
// Pack W[K][N] (fp32) -> MFMA B-fragment order (bf16).
// idx = ((nt*KS+ks)*64 + lane)*8 + j  ->  W[ks*32 + (lane>>4)*8 + j][nt*16 + (lane&15)]
// ---------------------------------------------------------------------------
template <int N, int K>
__device__ __forceinline__ void pack_one(int idx, const float* __restrict__ W,
                                         unsigned short* __restrict__ Wp) {
    constexpr int KS = K / 32;
    int j = idx & 7;
    int lane = (idx >> 3) & 63;
    int t = idx >> 9;
    int nt = t / KS, ks = t % KS;
    int n = nt * 16 + (lane & 15);
    int k = ks * 32 + (lane >> 4) * 8 + j;
    Wp[idx] = f2b(W[(size_t)k * N + n]);
}

// prep: zero cursor (idx < NNODES) + pack all 4 weights (idx >= NNODES)
__global__ __launch_bounds__(256) void prep_kernel(int* __restrict__ cursor,
                                                   const float* __restrict__ W1,
                                                   const float* __restrict__ W2,
                                                   const float* __restrict__ W3,
                                                   const float* __restrict__ W4,
                                                   unsigned short* __restrict__ Wp1,
                                                   unsigned short* __restrict__ Wp2,
                                                   unsigned short* __restrict__ Wp3,
                                                   unsigned short* __restrict__ Wp4) {
    int idx = blockIdx.x * 256 + threadIdx.x;
    if (idx < NNODES) { cursor[idx] = 0; return; }
    int p = idx - NNODES;
    if (p < 16384) pack_one<128, 128>(p, W1, Wp1);
    else if (p < 32768) pack_one<128, 128>(p - 16384, W2, Wp2);
    else if (p < 40960) pack_one<64, 128>(p - 32768, W3, Wp3);
    else if (p < 43008) pack_one<32, 64>(p - 40960, W4, Wp4);
}

// ---------------------------------------------------------------------------
// XCD-partitioned bucket fill, LDS-compacted (scan phase -> dense drain).
// ---------------------------------------------------------------------------
constexpr int NPART = 8;
constexpr int PSIZE = NNODES / NPART;   // 6250
constexpr int FCH = 1024;               // edges scanned per block (4/thread)
constexpr int QCAP = 320;               // matches: mean 128, sd ~10.6

__global__ __launch_bounds__(256) void fill_kernel(const int* __restrict__ src,
                                                   const int* __restrict__ dst,
                                                   const float* __restrict__ val,
                                                   int* __restrict__ cursor,
                                                   int2* __restrict__ buckets) {
    __shared__ int q_e[QCAP];
    __shared__ int q_d[QCAP];
    __shared__ int qcount;
    if (threadIdx.x == 0) qcount = 0;
    __syncthreads();

    int part = blockIdx.x % NPART;
    int chunk = blockIdx.x / NPART;
    int lo = part * PSIZE, hi = lo + PSIZE;
    int e0 = chunk * FCH + threadIdx.x * 4;

    int4 d4 = make_int4(-1, -1, -1, -1);
    if (e0 + 3 < NEDGES) {
        d4 = *reinterpret_cast<const int4*>(dst + e0);
    } else if (e0 < NEDGES) {
        d4.x = dst[e0];
        if (e0 + 1 < NEDGES) d4.y = dst[e0 + 1];
        if (e0 + 2 < NEDGES) d4.z = dst[e0 + 2];
    }
    int dd[4] = {d4.x, d4.y, d4.z, d4.w};
#pragma unroll
    for (int i = 0; i < 4; ++i) {
        int d = dd[i];
        if (d >= lo && d < hi) {
            int pos = atomicAdd(&qcount, 1);
            if (pos < QCAP) {
                q_e[pos] = e0 + i;
                q_d[pos] = d;
            } else {  // overflow fallback (statistically unreachable; correct anyway)
                int e = e0 + i;
                int p = atomicAdd(&cursor[d], 1);
                if (p < CAP)
                    buckets[(size_t)d * CAP + p] = make_int2(src[e], __float_as_int(val[e]));
            }
        }
    }
    __syncthreads();

    int n = qcount < QCAP ? qcount : QCAP;
    for (int i = threadIdx.x; i < n; i += 256) {
        int e = q_e[i];
        int d = q_d[i];
        int s = src[e];
        float v = val[e];
        int p = atomicAdd(&cursor[d], 1);
        if (p < CAP)
            buckets[(size_t)d * CAP + p] = make_int2(s, __float_as_int(v));
    }
}

// ---------------------------------------------------------------------------
// MFMA bf16 GEMM (layer 1 only): S1 = x @ W1, fp32 x converted in-register.
// ---------------------------------------------------------------------------
template <int N, int K>
__global__ __launch_bounds__(256) void mfma_gemm_f32_kernel(const float* __restrict__ H,
                                                            const unsigned short* __restrict__ Wp,
                                                            unsigned short* __restrict__ Sb) {
    constexpr int NT = N / 16, KS = K / 32;
    const int lane = threadIdx.x & 63;
    const int wave = threadIdx.x >> 6;
    const int waveRow = blockIdx.x * 64 + wave * 16;
    const int m = lane & 15, quad = lane >> 4;
    int arow = waveRow + m;
    if (arow >= NNODES) arow = NNODES - 1;      // clamp; stores are guarded

    f32x4 acc[NT];
#pragma unroll
    for (int nt = 0; nt < NT; ++nt) acc[nt] = (f32x4){0.f, 0.f, 0.f, 0.f};

#pragma unroll
    for (int ks = 0; ks < KS; ++ks) {
        const float* hp = H + (size_t)arow * K + ks * 32 + quad * 8;
        float4 a0 = *reinterpret_cast<const float4*>(hp);
        float4 a1 = *reinterpret_cast<const float4*>(hp + 4);
        short8 a;
        a[0] = (short)f2b(a0.x); a[1] = (short)f2b(a0.y);
        a[2] = (short)f2b(a0.z); a[3] = (short)f2b(a0.w);
        a[4] = (short)f2b(a1.x); a[5] = (short)f2b(a1.y);
        a[6] = (short)f2b(a1.z); a[7] = (short)f2b(a1.w);
#pragma unroll
        for (int nt = 0; nt < NT; ++nt) {
            short8 b = *reinterpret_cast<const short8*>(Wp + ((nt * KS + ks) * 64 + lane) * 8);
            acc[nt] = __builtin_amdgcn_mfma_f32_16x16x32_bf16(a, b, acc[nt], 0, 0, 0);
        }
    }

#pragma unroll
    for (int reg = 0; reg < 4; ++reg) {
        int grow = waveRow + quad * 4 + reg;
        if (grow < NNODES) {
#pragma unroll
            for (int nt = 0; nt < NT; ++nt)
                Sb[(size_t)grow * N + nt * 16 + m] = f2b(acc[nt][reg]);
        }
    }
}

// ---------------------------------------------------------------------------
// FUSED layer kernel: h = relu(agg(Sprev) + bias) staged in LDS, then
// Snext = h @ W via MFMA. 64 nodes/block.
//   Phase A: 4 threads/node, each owns NIN/4 cols; 2-edge unroll
//            (4 outstanding 16B row-gathers/thread).
//   Phase B: wave w -> LDS rows w*16..+15; a-frag = ds_read_b128 from the
//            padded tile (row stride NIN+8 bf16 = 16B-aligned).
// ---------------------------------------------------------------------------
template <int NIN, int NOUT>
__global__ __launch_bounds__(256) void layer_kernel(const unsigned short* __restrict__ Sprev,
                                                    const int2* __restrict__ buckets,
                                                    const int* __restrict__ counts,
                                                    const float* __restrict__ bias,
                                                    const unsigned short* __restrict__ Wp,
                                                    unsigned short* __restrict__ Snext) {
    constexpr int KS = NIN / 32;
    constexpr int NT = NOUT / 16;
    constexpr int CPT = NIN / 4;        // cols per thread in phase A (32 or 16)
    constexpr int NC8 = CPT / 8;        // ushort8 chunks per thread (4 or 2)
    constexpr int LROW = NIN + 8;       // LDS row stride in bf16 (16B-aligned pad)
    __shared__ unsigned short htile[64 * LROW];

    const int tid = threadIdx.x;
    const int nodeBase = blockIdx.x * 64;

    // ---- Phase A: pull-agg + bias + relu -> LDS ----
    {
        int nl = tid >> 2;              // node_local 0..63
        int q = tid & 3;
        int node = nodeBase + nl;
        float acc[CPT];
        if (node < NNODES) {
#pragma unroll
            for (int t = 0; t < CPT; ++t) acc[t] = bias[q * CPT + t];
            int cnt = counts[node];
            if (cnt > CAP) cnt = CAP;
            const int2* eb = buckets + (size_t)node * CAP;
            int j = 0;
            for (; j + 2 <= cnt; j += 2) {
                int4 ee = *reinterpret_cast<const int4*>(eb + j);
                const unsigned short* r0 = Sprev + (size_t)ee.x * NIN + q * CPT;
                const unsigned short* r1 = Sprev + (size_t)ee.z * NIN + q * CPT;
                ushort8 m0[NC8], m1[NC8];
#pragma unroll
                for (int c = 0; c < NC8; ++c) m0[c] = *reinterpret_cast<const ushort8*>(r0 + c * 8);
#pragma unroll
                for (int c = 0; c < NC8; ++c) m1[c] = *reinterpret_cast<const ushort8*>(r1 + c * 8);
                float v0 = __int_as_float(ee.y), v1 = __int_as_float(ee.w);
#pragma unroll
                for (int c = 0; c < NC8; ++c)
#pragma unroll
                    for (int t = 0; t < 8; ++t) {
                        acc[c * 8 + t] = fmaf(b2f(m0[c][t]), v0, acc[c * 8 + t]);
                        acc[c * 8 + t] = fmaf(b2f(m1[c][t]), v1, acc[c * 8 + t]);
                    }
            }
            if (j < cnt) {
                int2 e = eb[j];
                float v = __int_as_float(e.y);
                const unsigned short* r0 = Sprev + (size_t)e.x * NIN + q * CPT;
#pragma unroll
                for (int c = 0; c < NC8; ++c) {
                    ushort8 mr = *reinterpret_cast<const ushort8*>(r0 + c * 8);
#pragma unroll
                    for (int t = 0; t < 8; ++t)
                        acc[c * 8 + t] = fmaf(b2f(mr[t]), v, acc[c * 8 + t]);
                }
            }
        } else {
#pragma unroll
            for (int t = 0; t < CPT; ++t) acc[t] = 0.f;
        }
        unsigned short* lrow = &htile[nl * LROW + q * CPT];
#pragma unroll
        for (int c = 0; c < NC8; ++c) {
            ushort8 o;
#pragma unroll
            for (int t = 0; t < 8; ++t) o[t] = f2b(fmaxf(acc[c * 8 + t], 0.f));
            *reinterpret_cast<ushort8*>(lrow + c * 8) = o;
        }
    }
    __syncthreads();

    // ---- Phase B: MFMA gemm on the 64-row LDS tile ----
    {
        const int lane = tid & 63, wave = tid >> 6;
        const int m = lane & 15, quad = lane >> 4;
        const int lrow = wave * 16 + m;
        f32x4 acc[NT];
#pragma unroll
        for (int nt = 0; nt < NT; ++nt) acc[nt] = (f32x4){0.f, 0.f, 0.f, 0.f};
#pragma unroll
        for (int ks = 0; ks < KS; ++ks) {
            short8 a = *reinterpret_cast<const short8*>(&htile[lrow * LROW + ks * 32 + quad * 8]);
#pragma unroll
            for (int nt = 0; nt < NT; ++nt) {
                short8 b = *reinterpret_cast<const short8*>(Wp + ((nt * KS + ks) * 64 + lane) * 8);
                acc[nt] = __builtin_amdgcn_mfma_f32_16x16x32_bf16(a, b, acc[nt], 0, 0, 0);
            }
        }
#pragma unroll
        for (int reg = 0; reg < 4; ++reg) {
            int grow = nodeBase + wave * 16 + quad * 4 + reg;
            if (grow < NNODES) {
#pragma unroll
                for (int nt = 0; nt < NT; ++nt)
                    Snext[(size_t)grow * NOUT + nt * 16 + m] = f2b(acc[nt][reg]);
            }
        }
    }
}

// ---------------------------------------------------------------------------
// Final pull aggregation (layer 4): 32-wide, fp32 output, 4x edge unroll.
// ---------------------------------------------------------------------------
__global__ __launch_bounds__(256) void agg_out_kernel(const unsigned short* __restrict__ Sb,
                                                      const int2* __restrict__ buckets,
                                                      const int* __restrict__ counts,
                                                      const float* __restrict__ bias,
                                                      float* __restrict__ outp) {
    constexpr int N = 32;
    int node = blockIdx.x * 64 + threadIdx.x / 4;
    int cg = threadIdx.x % 4;
    if (node >= NNODES) return;
    int cnt = counts[node];
    if (cnt > CAP) cnt = CAP;
    const int2* eb = buckets + (size_t)node * CAP;
    float acc[8];
#pragma unroll
    for (int t = 0; t < 8; ++t) acc[t] = bias[cg * 8 + t];

    int j = 0;
    for (; j + 4 <= cnt; j += 4) {
        int4 ea = *reinterpret_cast<const int4*>(eb + j);
        int4 ec = *reinterpret_cast<const int4*>(eb + j + 2);
        const ushort8 m0 = *reinterpret_cast<const ushort8*>(Sb + (size_t)ea.x * N + cg * 8);
        const ushort8 m1 = *reinterpret_cast<const ushort8*>(Sb + (size_t)ea.z * N + cg * 8);
        const ushort8 m2 = *reinterpret_cast<const ushort8*>(Sb + (size_t)ec.x * N + cg * 8);
        const ushort8 m3 = *reinterpret_cast<const ushort8*>(Sb + (size_t)ec.z * N + cg * 8);
        float v0 = __int_as_float(ea.y), v1 = __int_as_float(ea.w);
        float v2 = __int_as_float(ec.y), v3 = __int_as_float(ec.w);
#pragma unroll
        for (int t = 0; t < 8; ++t) {
            acc[t] = fmaf(b2f(m0[t]), v0, acc[t]);
            acc[t] = fmaf(b2f(m1[t]), v1, acc[t]);
            acc[t] = fmaf(b2f(m2[t]), v2, acc[t]);
            acc[t] = fmaf(b2f(m3[t]), v3, acc[t]);
        }
    }
    for (; j < cnt; ++j) {
        int2 e = eb[j];
        float v = __int_as_float(e.y);
        const ushort8 mr = *reinterpret_cast<const ushort8*>(Sb + (size_t)e.x * N + cg * 8);
#pragma unroll
        for (int t = 0; t < 8; ++t) acc[t] = fmaf(b2f(mr[t]), v, acc[t]);
    }

    float* op = outp + (size_t)node * N + cg * 8;
    *reinterpret_cast<float4*>(op) = make_float4(acc[0], acc[1], acc[2], acc[3]);
    *reinterpret_cast<float4*>(op + 4) = make_float4(acc[4], acc[5], acc[6], acc[7]);
}

extern "C" void kernel_launch(void* const* d_in, const int* in_sizes, int n_in,
                              void* d_out, int out_size, void* d_ws, size_t ws_size,
                              hipStream_t stream) {
    const float* x   = (const float*)d_in[0];
    const int*   src = (const int*)d_in[1];
    const int*   dst = (const int*)d_in[2];
    const float* val = (const float*)d_in[3];
    const float* W1  = (const float*)d_in[4];
    const float* b1  = (const float*)d_in[5];
    const float* W2  = (const float*)d_in[6];
    const float* b2  = (const float*)d_in[7];
    const float* W3  = (const float*)d_in[8];
    const float* b3  = (const float*)d_in[9];
    const float* W4  = (const float*)d_in[10];
    const float* b4  = (const float*)d_in[11];
    float* out = (float*)d_out;

    unsigned short* P = (unsigned short*)d_ws;            // bf16 50000x128
    unsigned short* Q = P + (size_t)NNODES * 128;         // bf16 50000x128
    int2* buckets = (int2*)(Q + (size_t)NNODES * 128);    // NNODES*CAP int2 = 25.6 MB
    unsigned short* Wp1 = (unsigned short*)(buckets + (size_t)NNODES * CAP);
    unsigned short* Wp2 = Wp1 + 128 * 128;
    unsigned short* Wp3 = Wp2 + 128 * 128;
    unsigned short* Wp4 = Wp3 + 128 * 64;
    int* cursor = (int*)(Wp4 + 64 * 32);                  // NNODES (counter, then degree)

    const dim3 blk(256);
    const int grid64 = (NNODES + 63) / 64;                // 782
    const int prepGrid = (NNODES + 43008 + 255) / 256;
    const int fillGrid = ((NEDGES + FCH - 1) / FCH) * NPART;

    // ---- build padded-bucket adjacency + pack weights ----
    prep_kernel<<<prepGrid, blk, 0, stream>>>(cursor, W1, W2, W3, W4, Wp1, Wp2, Wp3, Wp4);
    fill_kernel<<<fillGrid, blk, 0, stream>>>(src, dst, val, cursor, buckets);

    // ---- Layer 1 GEMM: S1 = x @ W1 ----
    mfma_gemm_f32_kernel<128, 128><<<grid64, blk, 0, stream>>>(x, Wp1, Q);
    // ---- Fused layers: h_i = relu(agg(S_i)+b_i); S_{i+1} = h_i @ W_{i+1} ----
    layer_kernel<128, 128><<<grid64, blk, 0, stream>>>(Q, buckets, cursor, b1, Wp2, P);
    layer_kernel<128, 64><<<grid64, blk, 0, stream>>>(P, buckets, cursor, b2, Wp3, Q);
    layer_kernel<64, 32><<<grid64, blk, 0, stream>>>(Q, buckets, cursor, b3, Wp4, P);
    // ---- Layer 4 aggregation: out = agg(S4) + b4 (fp32) ----
    agg_out_kernel<<<grid64, blk, 0, stream>>>(P, buckets, cursor, b4, out);
}